// Round 15
// baseline (263.294 us; speedup 1.0000x reference)
//
#include <hip/hip_runtime.h>

#define BATCH 16
#define NQ 2048
#define NK 2048

typedef short s16x8 __attribute__((ext_vector_type(8)));
typedef __bf16 bf16x8 __attribute__((ext_vector_type(8)));
typedef float f32x16 __attribute__((ext_vector_type(16)));
typedef float f32x4 __attribute__((ext_vector_type(4)));
typedef int i32x4 __attribute__((ext_vector_type(4)));
typedef unsigned u32x2 __attribute__((ext_vector_type(2)));

static __device__ __forceinline__ unsigned short f2bf(float f) {
  unsigned u = __builtin_bit_cast(unsigned, f);
  u += 0x7FFFu + ((u >> 16) & 1u);   // round-to-nearest-even
  return (unsigned short)(u >> 16);
}

static __device__ __forceinline__ f32x16 mfma32(s16x8 a, s16x8 b, f32x16 c) {
  return __builtin_amdgcn_mfma_f32_32x32x16_bf16(
      __builtin_bit_cast(bf16x8, a), __builtin_bit_cast(bf16x8, b), c, 0, 0, 0);
}

static __device__ __forceinline__ f32x4 mfma16(s16x8 a, s16x8 b, f32x4 c) {
  return __builtin_amdgcn_mfma_f32_16x16x32_bf16(
      __builtin_bit_cast(bf16x8, a), __builtin_bit_cast(bf16x8, b), c, 0, 0, 0);
}

// p = exp(10*tanh(s) - 10) = exp2(-28.8539.../(e^(2s)+1)), e^(2s)=exp2(2.88539*s)
static __device__ __forceinline__ float score_p(float s) {
  float u = __builtin_amdgcn_exp2f(s * 2.885390081777927f);
  return __builtin_amdgcn_exp2f(-28.853900817779268f * __builtin_amdgcn_rcpf(u + 1.0f));
}

// WT[n][k] = W[k][n] * scale, cast to bf16.  Grid: (256, 2) x 256 thr.
__global__ void prep_wt(const float* __restrict__ Wk, unsigned short* __restrict__ WkT,
                        const float* __restrict__ Wq, unsigned short* __restrict__ WqT) {
  const float* W = blockIdx.y ? Wq : Wk;
  unsigned short* WT = blockIdx.y ? WqT : WkT;
  float scale = blockIdx.y ? 0.0625f : 1.0f;   // fold 1/sqrt(256) into Wq
  int idx = blockIdx.x * 256 + threadIdx.x;
  int n = idx >> 8, k = idx & 255;
  WT[n * 256 + k] = f2bf(W[k * 256 + n] * scale);
}

// Projection; output packed in 16x16x32-MFMA fragment order for 16-row tiles:
//   Yf[((t16*8 + kk)*64 + lane)*8 + j] = Y[row = t16*16 + (lane&15)]
//                                         [e  = kk*32 + (lane>>4)*8 + j]
__global__ __launch_bounds__(256, 2) void proj_kernel(
    const float* __restrict__ Xk, const unsigned short* __restrict__ WkT,
    unsigned short* __restrict__ Yk,
    const float* __restrict__ Xq, const unsigned short* __restrict__ WqT,
    unsigned short* __restrict__ Yq) {
  const float* X;
  const unsigned short* WT;
  unsigned short* Y;
  if (blockIdx.y == 0) { X = Xk; WT = WkT; Y = Yk; }
  else                 { X = Xq; WT = WqT; Y = Yq; }

  int tid = threadIdx.x;
  int wave = tid >> 6, lane = tid & 63;
  int l31 = lane & 31, kh = lane >> 5;
  int r0 = blockIdx.x * 128 + wave * 32;

  const float* xp = X + (size_t)(r0 + l31) * 256 + kh * 8;

  f32x16 acc[8];
#pragma unroll
  for (int ct = 0; ct < 8; ++ct)
#pragma unroll
    for (int i = 0; i < 16; ++i) acc[ct][i] = 0.0f;

#pragma unroll
  for (int kk = 0; kk < 16; ++kk) {
    f32x4 a0 = *(const f32x4*)(xp + kk * 16);
    f32x4 a1 = *(const f32x4*)(xp + kk * 16 + 4);
    s16x8 af;
#pragma unroll
    for (int j = 0; j < 4; ++j) {
      af[j]     = (short)f2bf(a0[j]);
      af[4 + j] = (short)f2bf(a1[j]);
    }
#pragma unroll
    for (int ct = 0; ct < 8; ++ct) {
      s16x8 bw = *(const s16x8*)(WT + (size_t)(ct * 32 + l31) * 256 + kk * 16 + kh * 8);
      acc[ct] = mfma32(af, bw, acc[ct]);
    }
  }

  // epilogue: scatter into 16-row-tile fragment order
  int kg2 = l31 >> 3, j = l31 & 7;
#pragma unroll
  for (int ct = 0; ct < 8; ++ct) {
#pragma unroll
    for (int r = 0; r < 16; ++r) {
      int rrow = (r & 3) + 8 * (r >> 2) + 4 * kh;
      int row = r0 + rrow;
      Y[((size_t)((row >> 4) * 8 + ct) * 64 + kg2 * 16 + (row & 15)) * 8 + j] =
          f2bf(acc[ct][r]);
    }
  }
}

// Fused adjacency-pack + scores + tanh-clip + mask + softmax, ONE-PASS,
// P stash in LDS (R10 layout), K prefetch via ROTATING 3x HALF-TILE buffers
// (X/Y/Z, 16 VGPR each = 48 total vs R14's 64-reg ping-pong whose overflow
// landed in AGPRs -> unified total >128 -> 1 block/CU). Target: ~115 total
// regs -> 4 waves/SIMD -> 2 blocks/CU (LDS 69.7 KB x2 fits 160 KB) WITH
// load-latency hiding (issue half-tile ~150 cyc before use).
// Adjacency: NT int4 loads + nibble/shfl-OR pack. Output: NT stores.
// XCD-aware remap: xcd = lin&7 owns batches {2*xcd, 2*xcd+1} (2 MB K / L2).
__global__ __launch_bounds__(512, 2) void attn_kernel(
    const unsigned short* __restrict__ Kf, const unsigned short* __restrict__ Qf,
    const int* __restrict__ adj, float* __restrict__ out) {
  int lin = blockIdx.y * 128 + blockIdx.x;
  int b  = (lin & 7) * 2 + ((lin >> 3) & 1);
  int qt = lin >> 4;                 // 0..127: 16-row tile within batch
  int q0 = qt * 16;
  int tid = threadIdx.x;
  int wave = tid >> 6, lane = tid & 63;
  int l15 = lane & 15, kg = lane >> 4;
  int colbase = wave * 256;

  __shared__ unsigned plds[8 * 16 * 64 * 2];  // 64 KB: P bf16 [wave][ct][lane][2]
  __shared__ unsigned lmask[8 * 144];         // mask words, row stride 9 (pad)
  __shared__ float wsum[8][16];
  __shared__ float rrecip[16];

  // ---- wave-local adjacency pack, NT int4 loads, 4-row chunks ----
  const i32x4* ap4 =
      (const i32x4*)(adj + ((size_t)b * NQ + q0) * (size_t)NK + colbase) + lane;
  unsigned* lm = lmask + wave * 144;
#pragma unroll
  for (int quad = 0; quad < 4; ++quad) {
    i32x4 av[4];
#pragma unroll
    for (int r4 = 0; r4 < 4; ++r4)
      av[r4] = __builtin_nontemporal_load(ap4 + (size_t)(quad * 4 + r4) * (NK / 4));
#pragma unroll
    for (int r4 = 0; r4 < 4; ++r4) {
      i32x4 v = av[r4];
      unsigned nib = (v[0] != 0 ? 1u : 0u) | (v[1] != 0 ? 2u : 0u) |
                     (v[2] != 0 ? 4u : 0u) | (v[3] != 0 ? 8u : 0u);
      unsigned m = nib << ((lane & 7) * 4);
      m |= __shfl_xor(m, 1);
      m |= __shfl_xor(m, 2);
      m |= __shfl_xor(m, 4);   // all 8 lanes of group g=lane>>3 now hold word g
      if ((lane & 7) == 0) lm[(quad * 4 + r4) * 9 + (lane >> 3)] = m;
    }
  }

  // Q fragments: global tile = b*128 + qt (8 KB, coalesced 1 KB loads)
  const unsigned short* qp = Qf + (size_t)(b * 128 + qt) * 8 * 512;
  s16x8 aq[8];
#pragma unroll
  for (int kk = 0; kk < 8; ++kk)
    aq[kk] = __builtin_nontemporal_load(
        (const s16x8*)(qp + ((size_t)kk * 64 + lane) * 8));

  // no barrier: lmask/plds slices are wave-local (lgkmcnt orders same-wave LDS)

  const unsigned short* kfb = Kf + (size_t)b * 128 * 8 * 512;
  unsigned* pl = plds + (wave * 16) * 128 + lane * 2;

  float rsum[4] = {0.0f, 0.0f, 0.0f, 0.0f};
  s16x8 X[4], Y[4], Z[4];   // rotating half-tile buffers (16 VGPR each)

#define ISSUE(CT, HALF, DST)                                                   \
  {                                                                            \
    const unsigned short* kpt = kfb + (size_t)(wave * 16 + (CT)) * 4096;       \
    _Pragma("unroll") for (int i = 0; i < 4; ++i)                              \
        DST[i] = *(const s16x8*)(kpt + ((size_t)((HALF)*4 + i) * 64 + lane) * 8); \
  }

#define SCORE(CT)                                                              \
  {                                                                            \
    unsigned shift = (unsigned)(((CT) & 1) * 16 + l15);                        \
    float p[4];                                                                \
    _Pragma("unroll") for (int r = 0; r < 4; ++r) {                            \
      unsigned mw = lm[(kg * 4 + r) * 9 + ((CT) >> 1)];                        \
      float e = score_p(acc[r]);                                               \
      p[r] = ((mw >> shift) & 1u) ? e : 0.0f;                                  \
      rsum[r] += p[r];                                                         \
    }                                                                          \
    u32x2 v;                                                                   \
    v[0] = (unsigned)f2bf(p[0]) | ((unsigned)f2bf(p[1]) << 16);                \
    v[1] = (unsigned)f2bf(p[2]) | ((unsigned)f2bf(p[3]) << 16);                \
    *(u32x2*)(pl + (CT)*128) = v;                                              \
  }

  // STEP(ct, A=h0 buf, B=h1 buf, C=spare): prefetch ct+1 while consuming ct
#define STEP(CT, A, B, C)                                                      \
  {                                                                            \
    f32x4 acc = {0.0f, 0.0f, 0.0f, 0.0f};                                      \
    ISSUE((CT) + 1, 0, C)                                                      \
    _Pragma("unroll") for (int i = 0; i < 4; ++i) acc = mfma16(aq[i], A[i], acc); \
    ISSUE((CT) + 1, 1, A)                                                      \
    _Pragma("unroll") for (int i = 0; i < 4; ++i) acc = mfma16(aq[4 + i], B[i], acc); \
    SCORE(CT)                                                                  \
  }

  ISSUE(0, 0, X)
  ISSUE(0, 1, Y)
  // 15 steps as 5 period-3 triples (buffers rotate (X,Y,Z)->(Z,X,Y)->(Y,Z,X))
#pragma unroll
  for (int t = 0; t < 5; ++t) {
    int c0 = t * 3;
    STEP(c0 + 0, X, Y, Z)
    STEP(c0 + 1, Z, X, Y)
    STEP(c0 + 2, Y, Z, X)
  }
  // tail: ct 15 (h0 in X, h1 in Y), no prefetch
  {
    f32x4 acc = {0.0f, 0.0f, 0.0f, 0.0f};
#pragma unroll
    for (int i = 0; i < 4; ++i) acc = mfma16(aq[i], X[i], acc);
#pragma unroll
    for (int i = 0; i < 4; ++i) acc = mfma16(aq[4 + i], Y[i], acc);
    SCORE(15)
  }
#undef ISSUE
#undef SCORE
#undef STEP

  // col-reduce within each 16-lane quarter (rows disjoint across quarters)
#pragma unroll
  for (int r = 0; r < 4; ++r) {
    float v = rsum[r];
    v += __shfl_xor(v, 1);
    v += __shfl_xor(v, 2);
    v += __shfl_xor(v, 4);
    v += __shfl_xor(v, 8);
    rsum[r] = v;
  }
  if (l15 == 0) {
#pragma unroll
    for (int r = 0; r < 4; ++r) wsum[wave][kg * 4 + r] = rsum[r];
  }
  __syncthreads();
  if (tid < 16) {
    float s = 0.0f;
#pragma unroll
    for (int w = 0; w < 8; ++w) s += wsum[w][tid];
    rrecip[tid] = 1.0f / s;
  }
  __syncthreads();

  float rc[4];
#pragma unroll
  for (int r = 0; r < 4; ++r) rc[r] = rrecip[kg * 4 + r];

  // read P back from LDS, normalize, NT-store
  float* op = out + ((size_t)b * NQ + q0 + kg * 4) * (size_t)NK + colbase + l15;
#pragma unroll 4
  for (int ct = 0; ct < 16; ++ct) {
    u32x2 v = *(const u32x2*)(pl + ct * 128);
    float p0 = __builtin_bit_cast(float, v[0] << 16);
    float p1 = __builtin_bit_cast(float, v[0] & 0xffff0000u);
    float p2 = __builtin_bit_cast(float, v[1] << 16);
    float p3 = __builtin_bit_cast(float, v[1] & 0xffff0000u);
    __builtin_nontemporal_store(p0 * rc[0], op + (size_t)0 * NK + ct * 16);
    __builtin_nontemporal_store(p1 * rc[1], op + (size_t)1 * NK + ct * 16);
    __builtin_nontemporal_store(p2 * rc[2], op + (size_t)2 * NK + ct * 16);
    __builtin_nontemporal_store(p3 * rc[3], op + (size_t)3 * NK + ct * 16);
  }
}

extern "C" void kernel_launch(void* const* d_in, const int* in_sizes, int n_in,
                              void* d_out, int out_size, void* d_ws, size_t ws_size,
                              hipStream_t stream) {
  const float* k_in = (const float*)d_in[0];
  const float* q_in = (const float*)d_in[1];
  const int* adj    = (const int*)d_in[2];
  const float* Wk   = (const float*)d_in[3];
  const float* Wq   = (const float*)d_in[4];
  float* out = (float*)d_out;

  char* ws = (char*)d_ws;
  unsigned short* WkT = (unsigned short*)(ws);                           // 128 KB
  unsigned short* WqT = (unsigned short*)(ws + (1u << 17));              // 128 KB
  unsigned short* Kf  = (unsigned short*)(ws + (1u << 18));              // 16 MB
  unsigned short* Qf  = (unsigned short*)(ws + (1u << 18) + (1u << 24)); // 16 MB

  prep_wt<<<dim3(256, 2), 256, 0, stream>>>(Wk, WkT, Wq, WqT);

  proj_kernel<<<dim3(256, 2), 256, 0, stream>>>(k_in, WkT, Kf, q_in, WqT, Qf);

  attn_kernel<<<dim3(128, 16), 512, 0, stream>>>(Kf, Qf, adj, out);
}

// Round 16
// 259.518 us; speedup vs baseline: 1.0146x; 1.0146x over previous
//
#include <hip/hip_runtime.h>

#define BATCH 16
#define NQ 2048
#define NK 2048

typedef short s16x8 __attribute__((ext_vector_type(8)));
typedef __bf16 bf16x8 __attribute__((ext_vector_type(8)));
typedef float f32x16 __attribute__((ext_vector_type(16)));
typedef float f32x4 __attribute__((ext_vector_type(4)));
typedef int i32x4 __attribute__((ext_vector_type(4)));
typedef unsigned u32x2 __attribute__((ext_vector_type(2)));

static __device__ __forceinline__ unsigned short f2bf(float f) {
  unsigned u = __builtin_bit_cast(unsigned, f);
  u += 0x7FFFu + ((u >> 16) & 1u);   // round-to-nearest-even
  return (unsigned short)(u >> 16);
}

static __device__ __forceinline__ f32x16 mfma32(s16x8 a, s16x8 b, f32x16 c) {
  return __builtin_amdgcn_mfma_f32_32x32x16_bf16(
      __builtin_bit_cast(bf16x8, a), __builtin_bit_cast(bf16x8, b), c, 0, 0, 0);
}

static __device__ __forceinline__ f32x4 mfma16(s16x8 a, s16x8 b, f32x4 c) {
  return __builtin_amdgcn_mfma_f32_16x16x32_bf16(
      __builtin_bit_cast(bf16x8, a), __builtin_bit_cast(bf16x8, b), c, 0, 0, 0);
}

// p = exp(10*tanh(s) - 10) = exp2(-28.8539.../(e^(2s)+1)), e^(2s)=exp2(2.88539*s)
static __device__ __forceinline__ float score_p(float s) {
  float u = __builtin_amdgcn_exp2f(s * 2.885390081777927f);
  return __builtin_amdgcn_exp2f(-28.853900817779268f * __builtin_amdgcn_rcpf(u + 1.0f));
}

// WT[n][k] = W[k][n] * scale, cast to bf16.  Grid: (256, 2) x 256 thr.
__global__ void prep_wt(const float* __restrict__ Wk, unsigned short* __restrict__ WkT,
                        const float* __restrict__ Wq, unsigned short* __restrict__ WqT) {
  const float* W = blockIdx.y ? Wq : Wk;
  unsigned short* WT = blockIdx.y ? WqT : WkT;
  float scale = blockIdx.y ? 0.0625f : 1.0f;   // fold 1/sqrt(256) into Wq
  int idx = blockIdx.x * 256 + threadIdx.x;
  int n = idx >> 8, k = idx & 255;
  WT[n * 256 + k] = f2bf(W[k * 256 + n] * scale);
}

// Projection; output packed in 16x16x32-MFMA fragment order for 16-row tiles:
//   Yf[((t16*8 + kk)*64 + lane)*8 + j] = Y[row = t16*16 + (lane&15)]
//                                         [e  = kk*32 + (lane>>4)*8 + j]
__global__ __launch_bounds__(256, 2) void proj_kernel(
    const float* __restrict__ Xk, const unsigned short* __restrict__ WkT,
    unsigned short* __restrict__ Yk,
    const float* __restrict__ Xq, const unsigned short* __restrict__ WqT,
    unsigned short* __restrict__ Yq) {
  const float* X;
  const unsigned short* WT;
  unsigned short* Y;
  if (blockIdx.y == 0) { X = Xk; WT = WkT; Y = Yk; }
  else                 { X = Xq; WT = WqT; Y = Yq; }

  int tid = threadIdx.x;
  int wave = tid >> 6, lane = tid & 63;
  int l31 = lane & 31, kh = lane >> 5;
  int r0 = blockIdx.x * 128 + wave * 32;

  const float* xp = X + (size_t)(r0 + l31) * 256 + kh * 8;

  f32x16 acc[8];
#pragma unroll
  for (int ct = 0; ct < 8; ++ct)
#pragma unroll
    for (int i = 0; i < 16; ++i) acc[ct][i] = 0.0f;

#pragma unroll
  for (int kk = 0; kk < 16; ++kk) {
    f32x4 a0 = *(const f32x4*)(xp + kk * 16);
    f32x4 a1 = *(const f32x4*)(xp + kk * 16 + 4);
    s16x8 af;
#pragma unroll
    for (int j = 0; j < 4; ++j) {
      af[j]     = (short)f2bf(a0[j]);
      af[4 + j] = (short)f2bf(a1[j]);
    }
#pragma unroll
    for (int ct = 0; ct < 8; ++ct) {
      s16x8 bw = *(const s16x8*)(WT + (size_t)(ct * 32 + l31) * 256 + kk * 16 + kh * 8);
      acc[ct] = mfma32(af, bw, acc[ct]);
    }
  }

  // epilogue: scatter into 16-row-tile fragment order
  int kg2 = l31 >> 3, j = l31 & 7;
#pragma unroll
  for (int ct = 0; ct < 8; ++ct) {
#pragma unroll
    for (int r = 0; r < 16; ++r) {
      int rrow = (r & 3) + 8 * (r >> 2) + 4 * kh;
      int row = r0 + rrow;
      Y[((size_t)((row >> 4) * 8 + ct) * 64 + kg2 * 16 + (row & 15)) * 8 + j] =
          f2bf(acc[ct][r]);
    }
  }
}

// Fused adjacency-pack + scores + tanh-clip + mask + softmax, ONE-PASS,
// P stash in LDS (R10 layout), K ping-pong prefetch (R14), plus:
//  - SPLIT MFMA CHAINS: each ct's 8 dependent MFMAs -> two independent
//    4-chains (acc0/acc1, interleaved) -> dependent latency per ct halves.
//  - BATCHED adjacency prologue: all 16 NT int4 loads issued before any
//    packing (64 transient VGPRs while aq is not yet live) -> one HBM
//    latency wave instead of four.
// Adjacency: NT int4 loads + nibble/shfl-OR pack. Output: NT stores.
// XCD-aware remap: xcd = lin&7 owns batches {2*xcd, 2*xcd+1} (2 MB K / L2).
__global__ __launch_bounds__(512, 2) void attn_kernel(
    const unsigned short* __restrict__ Kf, const unsigned short* __restrict__ Qf,
    const int* __restrict__ adj, float* __restrict__ out) {
  int lin = blockIdx.y * 128 + blockIdx.x;
  int b  = (lin & 7) * 2 + ((lin >> 3) & 1);
  int qt = lin >> 4;                 // 0..127: 16-row tile within batch
  int q0 = qt * 16;
  int tid = threadIdx.x;
  int wave = tid >> 6, lane = tid & 63;
  int l15 = lane & 15, kg = lane >> 4;
  int colbase = wave * 256;

  __shared__ unsigned plds[8 * 16 * 64 * 2];  // 64 KB: P bf16 [wave][ct][lane][2]
  __shared__ unsigned lmask[8 * 144];         // mask words, row stride 9 (pad)
  __shared__ float wsum[8][16];
  __shared__ float rrecip[16];

  // ---- wave-local adjacency pack: ALL 16 row-loads in flight first ----
  const i32x4* ap4 =
      (const i32x4*)(adj + ((size_t)b * NQ + q0) * (size_t)NK + colbase) + lane;
  unsigned* lm = lmask + wave * 144;
  {
    i32x4 av[16];
#pragma unroll
    for (int r = 0; r < 16; ++r)
      av[r] = __builtin_nontemporal_load(ap4 + (size_t)r * (NK / 4));
#pragma unroll
    for (int r = 0; r < 16; ++r) {
      i32x4 v = av[r];
      unsigned nib = (v[0] != 0 ? 1u : 0u) | (v[1] != 0 ? 2u : 0u) |
                     (v[2] != 0 ? 4u : 0u) | (v[3] != 0 ? 8u : 0u);
      unsigned m = nib << ((lane & 7) * 4);
      m |= __shfl_xor(m, 1);
      m |= __shfl_xor(m, 2);
      m |= __shfl_xor(m, 4);   // all 8 lanes of group g=lane>>3 now hold word g
      if ((lane & 7) == 0) lm[r * 9 + (lane >> 3)] = m;
    }
  }

  // Q fragments: global tile = b*128 + qt (8 KB, coalesced 1 KB loads)
  const unsigned short* qp = Qf + (size_t)(b * 128 + qt) * 8 * 512;
  s16x8 aq[8];
#pragma unroll
  for (int kk = 0; kk < 8; ++kk)
    aq[kk] = __builtin_nontemporal_load(
        (const s16x8*)(qp + ((size_t)kk * 64 + lane) * 8));

  // no barrier: lmask/plds slices are wave-local (lgkmcnt orders same-wave LDS)

  const unsigned short* kfb = Kf + (size_t)b * 128 * 8 * 512;
  unsigned* pl = plds + (wave * 16) * 128 + lane * 2;

  float rsum[4] = {0.0f, 0.0f, 0.0f, 0.0f};
  s16x8 bkA[8], bkB[8];

#define KLOAD(CT, DST)                                                         \
  {                                                                            \
    const unsigned short* kpt = kfb + (size_t)(wave * 16 + (CT)) * 4096;       \
    _Pragma("unroll") for (int kk = 0; kk < 8; ++kk)                           \
        DST[kk] = *(const s16x8*)(kpt + ((size_t)kk * 64 + lane) * 8);         \
  }

#define PROCESS(CT, BK)                                                        \
  {                                                                            \
    f32x4 acc0 = {0.0f, 0.0f, 0.0f, 0.0f};                                     \
    f32x4 acc1 = {0.0f, 0.0f, 0.0f, 0.0f};                                     \
    acc0 = mfma16(aq[0], BK[0], acc0);                                         \
    acc1 = mfma16(aq[4], BK[4], acc1);                                         \
    acc0 = mfma16(aq[1], BK[1], acc0);                                         \
    acc1 = mfma16(aq[5], BK[5], acc1);                                         \
    acc0 = mfma16(aq[2], BK[2], acc0);                                         \
    acc1 = mfma16(aq[6], BK[6], acc1);                                         \
    acc0 = mfma16(aq[3], BK[3], acc0);                                         \
    acc1 = mfma16(aq[7], BK[7], acc1);                                         \
    unsigned shift = (unsigned)(((CT) & 1) * 16 + l15);                        \
    float p[4];                                                                \
    _Pragma("unroll") for (int r = 0; r < 4; ++r) {                            \
      unsigned mw = lm[(kg * 4 + r) * 9 + ((CT) >> 1)];                        \
      float e = score_p(acc0[r] + acc1[r]);                                    \
      p[r] = ((mw >> shift) & 1u) ? e : 0.0f;                                  \
      rsum[r] += p[r];                                                         \
    }                                                                          \
    u32x2 v;                                                                   \
    v[0] = (unsigned)f2bf(p[0]) | ((unsigned)f2bf(p[1]) << 16);                \
    v[1] = (unsigned)f2bf(p[2]) | ((unsigned)f2bf(p[3]) << 16);                \
    *(u32x2*)(pl + (CT)*128) = v;                                              \
  }

  KLOAD(0, bkA)
#pragma unroll
  for (int cp = 0; cp < 8; ++cp) {
    KLOAD(2 * cp + 1, bkB)      // prefetch odd tile before consuming even
    PROCESS(2 * cp, bkA)
    if (cp < 7) KLOAD(2 * cp + 2, bkA)   // prefetch next even before odd
    PROCESS(2 * cp + 1, bkB)
  }
#undef KLOAD
#undef PROCESS

  // col-reduce within each 16-lane quarter (rows disjoint across quarters)
#pragma unroll
  for (int r = 0; r < 4; ++r) {
    float v = rsum[r];
    v += __shfl_xor(v, 1);
    v += __shfl_xor(v, 2);
    v += __shfl_xor(v, 4);
    v += __shfl_xor(v, 8);
    rsum[r] = v;
  }
  if (l15 == 0) {
#pragma unroll
    for (int r = 0; r < 4; ++r) wsum[wave][kg * 4 + r] = rsum[r];
  }
  __syncthreads();
  if (tid < 16) {
    float s = 0.0f;
#pragma unroll
    for (int w = 0; w < 8; ++w) s += wsum[w][tid];
    rrecip[tid] = 1.0f / s;
  }
  __syncthreads();

  float rc[4];
#pragma unroll
  for (int r = 0; r < 4; ++r) rc[r] = rrecip[kg * 4 + r];

  // read P back from LDS, normalize, NT-store
  float* op = out + ((size_t)b * NQ + q0 + kg * 4) * (size_t)NK + colbase + l15;
#pragma unroll 4
  for (int ct = 0; ct < 16; ++ct) {
    u32x2 v = *(const u32x2*)(pl + ct * 128);
    float p0 = __builtin_bit_cast(float, v[0] << 16);
    float p1 = __builtin_bit_cast(float, v[0] & 0xffff0000u);
    float p2 = __builtin_bit_cast(float, v[1] << 16);
    float p3 = __builtin_bit_cast(float, v[1] & 0xffff0000u);
    __builtin_nontemporal_store(p0 * rc[0], op + (size_t)0 * NK + ct * 16);
    __builtin_nontemporal_store(p1 * rc[1], op + (size_t)1 * NK + ct * 16);
    __builtin_nontemporal_store(p2 * rc[2], op + (size_t)2 * NK + ct * 16);
    __builtin_nontemporal_store(p3 * rc[3], op + (size_t)3 * NK + ct * 16);
  }
}

extern "C" void kernel_launch(void* const* d_in, const int* in_sizes, int n_in,
                              void* d_out, int out_size, void* d_ws, size_t ws_size,
                              hipStream_t stream) {
  const float* k_in = (const float*)d_in[0];
  const float* q_in = (const float*)d_in[1];
  const int* adj    = (const int*)d_in[2];
  const float* Wk   = (const float*)d_in[3];
  const float* Wq   = (const float*)d_in[4];
  float* out = (float*)d_out;

  char* ws = (char*)d_ws;
  unsigned short* WkT = (unsigned short*)(ws);                           // 128 KB
  unsigned short* WqT = (unsigned short*)(ws + (1u << 17));              // 128 KB
  unsigned short* Kf  = (unsigned short*)(ws + (1u << 18));              // 16 MB
  unsigned short* Qf  = (unsigned short*)(ws + (1u << 18) + (1u << 24)); // 16 MB

  prep_wt<<<dim3(256, 2), 256, 0, stream>>>(Wk, WkT, Wq, WqT);

  proj_kernel<<<dim3(256, 2), 256, 0, stream>>>(k_in, WkT, Kf, q_in, WqT, Qf);

  attn_kernel<<<dim3(128, 16), 512, 0, stream>>>(Kf, Qf, adj, out);
}

// Round 17
// 238.892 us; speedup vs baseline: 1.1021x; 1.0863x over previous
//
#include <hip/hip_runtime.h>

#define BATCH 16
#define NQ 2048
#define NK 2048

typedef short s16x8 __attribute__((ext_vector_type(8)));
typedef __bf16 bf16x8 __attribute__((ext_vector_type(8)));
typedef float f32x16 __attribute__((ext_vector_type(16)));
typedef float f32x4 __attribute__((ext_vector_type(4)));
typedef int i32x4 __attribute__((ext_vector_type(4)));
typedef unsigned u32x2 __attribute__((ext_vector_type(2)));

static __device__ __forceinline__ unsigned short f2bf(float f) {
  unsigned u = __builtin_bit_cast(unsigned, f);
  u += 0x7FFFu + ((u >> 16) & 1u);   // round-to-nearest-even
  return (unsigned short)(u >> 16);
}

static __device__ __forceinline__ f32x16 mfma32(s16x8 a, s16x8 b, f32x16 c) {
  return __builtin_amdgcn_mfma_f32_32x32x16_bf16(
      __builtin_bit_cast(bf16x8, a), __builtin_bit_cast(bf16x8, b), c, 0, 0, 0);
}

static __device__ __forceinline__ f32x4 mfma16(s16x8 a, s16x8 b, f32x4 c) {
  return __builtin_amdgcn_mfma_f32_16x16x32_bf16(
      __builtin_bit_cast(bf16x8, a), __builtin_bit_cast(bf16x8, b), c, 0, 0, 0);
}

// p = exp(10*tanh(s) - 10) = exp2(-28.8539.../(e^(2s)+1)), e^(2s)=exp2(2.88539*s)
static __device__ __forceinline__ float score_p(float s) {
  float u = __builtin_amdgcn_exp2f(s * 2.885390081777927f);
  return __builtin_amdgcn_exp2f(-28.853900817779268f * __builtin_amdgcn_rcpf(u + 1.0f));
}

// WT[n][k] = W[k][n] * scale, cast to bf16.  Grid: (256, 2) x 256 thr.
__global__ void prep_wt(const float* __restrict__ Wk, unsigned short* __restrict__ WkT,
                        const float* __restrict__ Wq, unsigned short* __restrict__ WqT) {
  const float* W = blockIdx.y ? Wq : Wk;
  unsigned short* WT = blockIdx.y ? WqT : WkT;
  float scale = blockIdx.y ? 0.0625f : 1.0f;   // fold 1/sqrt(256) into Wq
  int idx = blockIdx.x * 256 + threadIdx.x;
  int n = idx >> 8, k = idx & 255;
  WT[n * 256 + k] = f2bf(W[k * 256 + n] * scale);
}

// Projection; output packed in 16x16x32-MFMA fragment order for 16-row tiles:
//   Yf[((t16*8 + kk)*64 + lane)*8 + j] = Y[row = t16*16 + (lane&15)]
//                                         [e  = kk*32 + (lane>>4)*8 + j]
__global__ __launch_bounds__(256, 2) void proj_kernel(
    const float* __restrict__ Xk, const unsigned short* __restrict__ WkT,
    unsigned short* __restrict__ Yk,
    const float* __restrict__ Xq, const unsigned short* __restrict__ WqT,
    unsigned short* __restrict__ Yq) {
  const float* X;
  const unsigned short* WT;
  unsigned short* Y;
  if (blockIdx.y == 0) { X = Xk; WT = WkT; Y = Yk; }
  else                 { X = Xq; WT = WqT; Y = Yq; }

  int tid = threadIdx.x;
  int wave = tid >> 6, lane = tid & 63;
  int l31 = lane & 31, kh = lane >> 5;
  int r0 = blockIdx.x * 128 + wave * 32;

  const float* xp = X + (size_t)(r0 + l31) * 256 + kh * 8;

  f32x16 acc[8];
#pragma unroll
  for (int ct = 0; ct < 8; ++ct)
#pragma unroll
    for (int i = 0; i < 16; ++i) acc[ct][i] = 0.0f;

#pragma unroll
  for (int kk = 0; kk < 16; ++kk) {
    f32x4 a0 = *(const f32x4*)(xp + kk * 16);
    f32x4 a1 = *(const f32x4*)(xp + kk * 16 + 4);
    s16x8 af;
#pragma unroll
    for (int j = 0; j < 4; ++j) {
      af[j]     = (short)f2bf(a0[j]);
      af[4 + j] = (short)f2bf(a1[j]);
    }
#pragma unroll
    for (int ct = 0; ct < 8; ++ct) {
      s16x8 bw = *(const s16x8*)(WT + (size_t)(ct * 32 + l31) * 256 + kk * 16 + kh * 8);
      acc[ct] = mfma32(af, bw, acc[ct]);
    }
  }

  // epilogue: scatter into 16-row-tile fragment order
  int kg2 = l31 >> 3, j = l31 & 7;
#pragma unroll
  for (int ct = 0; ct < 8; ++ct) {
#pragma unroll
    for (int r = 0; r < 16; ++r) {
      int rrow = (r & 3) + 8 * (r >> 2) + 4 * kh;
      int row = r0 + rrow;
      Y[((size_t)((row >> 4) * 8 + ct) * 64 + kg2 * 16 + (row & 15)) * 8 + j] =
          f2bf(acc[ct][r]);
    }
  }
}

// Fused adjacency-pack + scores + tanh-clip + mask + softmax, ONE-PASS,
// 32 Q-ROWS PER BLOCK (two 16-row subtiles A/B): each loaded K fragment
// feeds TWO MFMAs, halving total K re-read volume (2 GB -> 1 GB). Theory:
// R10..R16 invariance at ~205 us across occupancy/prefetch says the kernel
// is K-stream (L2/L3) bandwidth-bound, so raise FLOPs/K-byte.
// Grid: (64, 16) = 1024 blocks, 512 threads (8 waves); wave w owns cols
// [w*256, w*256+256) as 16 col-tiles of 16. K ping-pong prefetch (R14).
// P stash in LDS 128 KB + lmask 9 KB -> ~139 KB -> 1 block/CU by LDS;
// __launch_bounds__(512,1) grants the 256-reg budget (aqA/B 64 + bk 64 +
// misc fits, no spill). R14 proved 1 block/CU + ping-pong holds throughput.
// Adjacency: NT int4 loads (2 chunks of 16 rows) + nibble/shfl-OR pack.
// Output: NT stores. XCD remap: xcd = lin&7 owns batches {2*xcd, 2*xcd+1}.
__global__ __launch_bounds__(512, 1) void attn_kernel(
    const unsigned short* __restrict__ Kf, const unsigned short* __restrict__ Qf,
    const int* __restrict__ adj, float* __restrict__ out) {
  int lin = blockIdx.y * 64 + blockIdx.x;
  int b  = (lin & 7) * 2 + ((lin >> 3) & 1);
  int qt = lin >> 4;                 // 0..63: 32-row tile within batch
  int q0 = qt * 32;
  int tid = threadIdx.x;
  int wave = tid >> 6, lane = tid & 63;
  int l15 = lane & 15, kg = lane >> 4;
  int colbase = wave * 256;

  __shared__ unsigned plds[8 * 16 * 256];  // 128 KB: [wave][ct][A:128|B:128]
  __shared__ unsigned lmask[8 * 288];      // 9 KB: 32 rows x 8 words, stride 9
  __shared__ float wsum[8][32];
  __shared__ float rrecip[32];

  // ---- wave-local adjacency pack: 2 chunks of 16 rows, loads batched ----
  const i32x4* ap4 =
      (const i32x4*)(adj + ((size_t)b * NQ + q0) * (size_t)NK + colbase) + lane;
  unsigned* lm = lmask + wave * 288;
#pragma unroll
  for (int chunk = 0; chunk < 2; ++chunk) {
    i32x4 av[16];
#pragma unroll
    for (int r = 0; r < 16; ++r)
      av[r] = __builtin_nontemporal_load(ap4 + (size_t)(chunk * 16 + r) * (NK / 4));
#pragma unroll
    for (int r = 0; r < 16; ++r) {
      i32x4 v = av[r];
      unsigned nib = (v[0] != 0 ? 1u : 0u) | (v[1] != 0 ? 2u : 0u) |
                     (v[2] != 0 ? 4u : 0u) | (v[3] != 0 ? 8u : 0u);
      unsigned m = nib << ((lane & 7) * 4);
      m |= __shfl_xor(m, 1);
      m |= __shfl_xor(m, 2);
      m |= __shfl_xor(m, 4);   // all 8 lanes of group g=lane>>3 now hold word g
      if ((lane & 7) == 0) lm[(chunk * 16 + r) * 9 + (lane >> 3)] = m;
    }
  }

  // Q fragments for subtiles A (rows q0..q0+15) and B (rows q0+16..q0+31)
  const unsigned short* qpA = Qf + (size_t)(b * 128 + 2 * qt) * 4096;
  s16x8 aqA[8], aqB[8];
#pragma unroll
  for (int kk = 0; kk < 8; ++kk) {
    aqA[kk] = __builtin_nontemporal_load(
        (const s16x8*)(qpA + ((size_t)kk * 64 + lane) * 8));
    aqB[kk] = __builtin_nontemporal_load(
        (const s16x8*)(qpA + 4096 + ((size_t)kk * 64 + lane) * 8));
  }

  // no barrier: lmask/plds slices are wave-local (lgkmcnt orders same-wave LDS)

  const unsigned short* kfb = Kf + (size_t)b * 128 * 4096;
  unsigned* pl = plds + wave * 4096 + lane * 2;

  float rsumA[4] = {0.0f, 0.0f, 0.0f, 0.0f};
  float rsumB[4] = {0.0f, 0.0f, 0.0f, 0.0f};
  s16x8 bkX[8], bkY[8];

#define KLOAD(CT, DST)                                                         \
  {                                                                            \
    const unsigned short* kpt = kfb + (size_t)(wave * 16 + (CT)) * 4096;       \
    _Pragma("unroll") for (int kk = 0; kk < 8; ++kk)                           \
        DST[kk] = *(const s16x8*)(kpt + ((size_t)kk * 64 + lane) * 8);         \
  }

#define PROCESS(CT, BK)                                                        \
  {                                                                            \
    f32x4 accA = {0.0f, 0.0f, 0.0f, 0.0f};                                     \
    f32x4 accB = {0.0f, 0.0f, 0.0f, 0.0f};                                     \
    _Pragma("unroll") for (int kk = 0; kk < 8; ++kk) {                         \
      accA = mfma16(aqA[kk], BK[kk], accA);                                    \
      accB = mfma16(aqB[kk], BK[kk], accB);                                    \
    }                                                                          \
    unsigned shift = (unsigned)(((CT) & 1) * 16 + l15);                        \
    float pA[4], pB[4];                                                        \
    _Pragma("unroll") for (int r = 0; r < 4; ++r) {                            \
      unsigned mwA = lm[(kg * 4 + r) * 9 + ((CT) >> 1)];                       \
      unsigned mwB = lm[(16 + kg * 4 + r) * 9 + ((CT) >> 1)];                  \
      float eA = score_p(accA[r]);                                             \
      float eB = score_p(accB[r]);                                             \
      pA[r] = ((mwA >> shift) & 1u) ? eA : 0.0f;                               \
      pB[r] = ((mwB >> shift) & 1u) ? eB : 0.0f;                               \
      rsumA[r] += pA[r];                                                       \
      rsumB[r] += pB[r];                                                       \
    }                                                                          \
    u32x2 vA, vB;                                                              \
    vA[0] = (unsigned)f2bf(pA[0]) | ((unsigned)f2bf(pA[1]) << 16);             \
    vA[1] = (unsigned)f2bf(pA[2]) | ((unsigned)f2bf(pA[3]) << 16);             \
    vB[0] = (unsigned)f2bf(pB[0]) | ((unsigned)f2bf(pB[1]) << 16);             \
    vB[1] = (unsigned)f2bf(pB[2]) | ((unsigned)f2bf(pB[3]) << 16);             \
    *(u32x2*)(pl + (CT)*256) = vA;                                             \
    *(u32x2*)(pl + (CT)*256 + 128) = vB;                                       \
  }

  KLOAD(0, bkX)
#pragma unroll
  for (int cp = 0; cp < 8; ++cp) {
    KLOAD(2 * cp + 1, bkY)      // prefetch odd tile before consuming even
    PROCESS(2 * cp, bkX)
    if (cp < 7) KLOAD(2 * cp + 2, bkX)   // prefetch next even before odd
    PROCESS(2 * cp + 1, bkY)
  }
#undef KLOAD
#undef PROCESS

  // col-reduce within each 16-lane quarter (rows disjoint across quarters)
#pragma unroll
  for (int r = 0; r < 4; ++r) {
    float vA = rsumA[r], vB = rsumB[r];
    vA += __shfl_xor(vA, 1);  vB += __shfl_xor(vB, 1);
    vA += __shfl_xor(vA, 2);  vB += __shfl_xor(vB, 2);
    vA += __shfl_xor(vA, 4);  vB += __shfl_xor(vB, 4);
    vA += __shfl_xor(vA, 8);  vB += __shfl_xor(vB, 8);
    rsumA[r] = vA;  rsumB[r] = vB;
  }
  if (l15 == 0) {
#pragma unroll
    for (int r = 0; r < 4; ++r) {
      wsum[wave][kg * 4 + r]      = rsumA[r];
      wsum[wave][16 + kg * 4 + r] = rsumB[r];
    }
  }
  __syncthreads();
  if (tid < 32) {
    float s = 0.0f;
#pragma unroll
    for (int w = 0; w < 8; ++w) s += wsum[w][tid];
    rrecip[tid] = 1.0f / s;
  }
  __syncthreads();

  float rcA[4], rcB[4];
#pragma unroll
  for (int r = 0; r < 4; ++r) {
    rcA[r] = rrecip[kg * 4 + r];
    rcB[r] = rrecip[16 + kg * 4 + r];
  }

  // read P back from LDS, normalize, NT-store
  float* opA = out + ((size_t)b * NQ + q0 + kg * 4) * (size_t)NK + colbase + l15;
  float* opB = opA + (size_t)16 * NK;
#pragma unroll 4
  for (int ct = 0; ct < 16; ++ct) {
    u32x2 vA = *(const u32x2*)(pl + ct * 256);
    u32x2 vB = *(const u32x2*)(pl + ct * 256 + 128);
#pragma unroll
    for (int r = 0; r < 4; ++r) {
      unsigned w = (r < 2) ? vA[0] : vA[1];
      float p = __builtin_bit_cast(float, (r & 1) ? (w & 0xffff0000u) : (w << 16));
      __builtin_nontemporal_store(p * rcA[r], opA + (size_t)r * NK + ct * 16);
    }
#pragma unroll
    for (int r = 0; r < 4; ++r) {
      unsigned w = (r < 2) ? vB[0] : vB[1];
      float p = __builtin_bit_cast(float, (r & 1) ? (w & 0xffff0000u) : (w << 16));
      __builtin_nontemporal_store(p * rcB[r], opB + (size_t)r * NK + ct * 16);
    }
  }
}

extern "C" void kernel_launch(void* const* d_in, const int* in_sizes, int n_in,
                              void* d_out, int out_size, void* d_ws, size_t ws_size,
                              hipStream_t stream) {
  const float* k_in = (const float*)d_in[0];
  const float* q_in = (const float*)d_in[1];
  const int* adj    = (const int*)d_in[2];
  const float* Wk   = (const float*)d_in[3];
  const float* Wq   = (const float*)d_in[4];
  float* out = (float*)d_out;

  char* ws = (char*)d_ws;
  unsigned short* WkT = (unsigned short*)(ws);                           // 128 KB
  unsigned short* WqT = (unsigned short*)(ws + (1u << 17));              // 128 KB
  unsigned short* Kf  = (unsigned short*)(ws + (1u << 18));              // 16 MB
  unsigned short* Qf  = (unsigned short*)(ws + (1u << 18) + (1u << 24)); // 16 MB

  prep_wt<<<dim3(256, 2), 256, 0, stream>>>(Wk, WkT, Wq, WqT);

  proj_kernel<<<dim3(256, 2), 256, 0, stream>>>(k_in, WkT, Kf, q_in, WqT, Qf);

  attn_kernel<<<dim3(64, 16), 512, 0, stream>>>(Kf, Qf, adj, out);
}